// Round 18
// baseline (342.813 us; speedup 1.0000x reference)
//
#include <hip/hip_runtime.h>
#include <math.h>

#define NEG_SLOPE 0.2f
#define CNT_SHIFT 44
#define LOW_MASK ((1ULL << CNT_SHIFT) - 1)
#define EA_SCALE 262144.0f          // 2^18 fixed-point for edge_attr sums
#define EA_INV (1.0f / 262144.0f)

typedef float f2 __attribute__((ext_vector_type(2)));
__device__ __forceinline__ f2 max2(f2 a, f2 b) { return __builtin_elementwise_max(a, b); }
__device__ __forceinline__ f2 lrelu2(f2 m) { return max2(m, m * NEG_SLOPE); }

__device__ __forceinline__ float lrelu(float x) { return fmaxf(x, NEG_SLOPE * x); }
__device__ __forceinline__ float elu1(float x) { return x > 0.f ? x : __expf(x) - 1.f; }

// Record layout (16B): {src_bits, ea, ev0, ev1}

// ---- k0p: single u64 atomic per edge (rank capture). At the ~21 G
//      scattered-atomics/s wall (flat: R13/R15/R16/R17). ----
__global__ void k0p(const int* __restrict__ dst, const float* __restrict__ ea,
                    unsigned long long* __restrict__ packed,
                    unsigned short* __restrict__ rankA, int E) {
    int t = blockIdx.x * blockDim.x + threadIdx.x;
    if (t >= E) return;
    int d = dst[t];
    unsigned long long inc = (1ULL << CNT_SHIFT)
                           | (unsigned long long)__float2uint_rn(ea[t] * EA_SCALE);
    unsigned long long old = atomicAdd(&packed[d], inc);
    rankA[t] = (unsigned short)(old >> CNT_SHIFT);
}

// ---- kscanA: per-block inclusive scan of (cnt[i]+1); unpack cnt/asum ----
__global__ void kscanA(const unsigned long long* __restrict__ packed,
                       int* __restrict__ rowstart, int* __restrict__ bsum,
                       int* __restrict__ cntA, float* __restrict__ asumA, int N) {
    __shared__ int sm[256];
    int t = threadIdx.x;
    int i = blockIdx.x * 256 + t;
    int v = 0;
    if (i < N) {
        unsigned long long p = packed[i];
        int c = (int)(p >> CNT_SHIFT);
        cntA[i] = c;
        asumA[i] = (float)(p & LOW_MASK) * EA_INV;
        v = c + 1;
    }
    sm[t] = v;
    __syncthreads();
    for (int off = 1; off < 256; off <<= 1) {
        int u = (t >= off) ? sm[t - off] : 0;
        __syncthreads();
        sm[t] += u;
        __syncthreads();
    }
    if (i < N) rowstart[i] = sm[t] - v;
    if (t == 255) bsum[blockIdx.x] = sm[255];
}

__global__ void kscanB(int* __restrict__ bsum, int B) {
    __shared__ int sm[512];
    int t = threadIdx.x;
    int v = (t < B) ? bsum[t] : 0;
    sm[t] = v;
    __syncthreads();
    for (int off = 1; off < 512; off <<= 1) {
        int u = (t >= off) ? sm[t - off] : 0;
        __syncthreads();
        sm[t] += u;
        __syncthreads();
    }
    if (t < B) bsum[t] = sm[t] - v;  // exclusive block offsets
}

__global__ void kscanC(int* __restrict__ rowstart, const int* __restrict__ bsum, int N) {
    int i = blockIdx.x * blockDim.x + threadIdx.x;
    if (i < N) rowstart[i] += bsum[i >> 8];
}

// ---- kscatter: pos = rowst[d] + rank[t]; zero atomics, idempotent.
//      Computes the layer-1 logit/exp (hidden under the scattered write). ----
__global__ void kscatter(const int* __restrict__ srcA, const int* __restrict__ dstA,
                         const float* __restrict__ ea, const float* __restrict__ x,
                         const float* __restrict__ asumA,
                         const int* __restrict__ cntA, const int* __restrict__ rowstart,
                         const unsigned short* __restrict__ rankA,
                         const float* __restrict__ Wl, const float* __restrict__ bl,
                         const float* __restrict__ Wr, const float* __restrict__ br,
                         const float* __restrict__ We, const float* __restrict__ att,
                         float4* __restrict__ rec, int E, int Et) {
    __shared__ float sW[7][64];
    if (threadIdx.x < 64) {
        int d = threadIdx.x;
        sW[0][d] = Wl[d];  sW[1][d] = Wl[64 + d];
        sW[2][d] = We[d];  sW[3][d] = att[d];
        sW[4][d] = Wr[d];  sW[5][d] = Wr[64 + d];
        sW[6][d] = bl[d] + br[d];
    }
    __syncthreads();
    int t = blockIdx.x * blockDim.x + threadIdx.x;
    if (t >= Et) return;
    int s, d, pos; float eav;
    if (t < E) {
        d = dstA[t]; s = srcA[t]; eav = ea[t];
        int r = min((int)rankA[t], cntA[d] - 1);   // defensive clamp (replay safety)
        pos = rowstart[d] + r;
    } else {
        d = t - E; s = d;
        int cd = cntA[d];
        pos = rowstart[d] + cd;
        eav = asumA[d] / fmaxf((float)cd, 1.0f);
    }
    float2 xs = ((const float2*)x)[s];
    float2 xd = ((const float2*)x)[d];
    float l0 = 0.f, l1 = 0.f;
    #pragma unroll
    for (int c = 0; c < 32; ++c) {
        float m0 = xd.x * sW[4][c] + xd.y * sW[5][c] + sW[6][c]
                 + xs.x * sW[0][c] + xs.y * sW[1][c] + eav * sW[2][c];
        l0 += lrelu(m0) * sW[3][c];
        int c2 = c + 32;
        float m1 = xd.x * sW[4][c2] + xd.y * sW[5][c2] + sW[6][c2]
                 + xs.x * sW[0][c2] + xs.y * sW[1][c2] + eav * sW[2][c2];
        l1 += lrelu(m1) * sW[3][c2];
    }
    rec[pos] = make_float4(__int_as_float(s), eav, __expf(l0), __expf(l1));
}

// ---- kL1: light segmented moment-sum. 16 lanes per node; 16B rec +
//      8B x[src] regather (L2-hot 800KB table). ----
__global__ void kL1(const float4* __restrict__ rec, const float* __restrict__ x,
                    const int* __restrict__ rowst, const int* __restrict__ cntA,
                    float* __restrict__ dstat, int N) {
    int g = threadIdx.x >> 4, l16 = threadIdx.x & 15;
    int n = blockIdx.x * 16 + g;
    if (n >= N) return;
    int start = rowst[n], len = cntA[n] + 1;
    float pd0 = 0.f, pd1 = 0.f, pa0 = 0.f, pa1 = 0.f, pb0 = 0.f, pb1 = 0.f;
    for (int i = l16; i < len; i += 16) {
        float4 q = rec[start + i];            // {src_bits, ea, ev0, ev1}
        float2 xs = ((const float2*)x)[__float_as_int(q.x)];
        pd0 += q.z;        pd1 += q.w;
        pa0 += q.z * xs.x; pa1 += q.w * xs.x;
        pb0 += q.z * xs.y; pb1 += q.w * xs.y;
    }
    #pragma unroll
    for (int m = 1; m < 16; m <<= 1) {
        pd0 += __shfl_xor(pd0, m); pd1 += __shfl_xor(pd1, m);
        pa0 += __shfl_xor(pa0, m); pa1 += __shfl_xor(pa1, m);
        pb0 += __shfl_xor(pb0, m); pb1 += __shfl_xor(pb1, m);
    }
    if (l16 == 0) {
        float* ps = &dstat[(size_t)n * 6];
        ps[0] = pd0; ps[1] = pd1;
        ps[2] = pa0; ps[3] = pa1;
        ps[4] = pb0; ps[5] = pb1;
    }
}

// ---- hcomp: shared h reconstruction (used by k3a stats pass and k3c) ----
__device__ __forceinline__ float hcomp(const float* __restrict__ dstat,
                                       const float* __restrict__ x,
                                       const float* __restrict__ Wl,
                                       const float* __restrict__ bl,
                                       const float* __restrict__ bias1,
                                       const float* __restrict__ skW,
                                       const float* __restrict__ skb,
                                       int n, int d) {
    int h2 = d >> 5;
    const float* ps = &dstat[(size_t)n * 6];
    float den = ps[h2], t0 = ps[2 + h2], t1 = ps[4 + h2];
    float agg = t0 * Wl[d] + t1 * Wl[64 + d] + den * bl[d];
    return agg / (den + 1e-16f) + bias1[d]
         + x[2 * n] * skW[d] + x[2 * n + 1] * skW[64 + d] + skb[d];
}

// ---- k3a: BN partials only (h recomputed, never materialized) ----
__global__ void k3a(const float* __restrict__ x, const float* __restrict__ dstat,
                    const float* __restrict__ Wl, const float* __restrict__ bl,
                    const float* __restrict__ bias1,
                    const float* __restrict__ skW, const float* __restrict__ skb,
                    float* __restrict__ partial, int N) {
    __shared__ float sv[256], sq[256];
    size_t total = (size_t)N * 64;
    size_t stride = (size_t)gridDim.x * blockDim.x;
    float s = 0.f, q = 0.f;
    for (size_t idx = (size_t)blockIdx.x * blockDim.x + threadIdx.x; idx < total; idx += stride) {
        int n = (int)(idx >> 6), d = (int)(idx & 63);
        float hv = hcomp(dstat, x, Wl, bl, bias1, skW, skb, n, d);
        s += hv; q += hv * hv;
    }
    sv[threadIdx.x] = s; sq[threadIdx.x] = q;
    __syncthreads();
    if (threadIdx.x < 64) {
        float a = sv[threadIdx.x] + sv[threadIdx.x + 64] + sv[threadIdx.x + 128] + sv[threadIdx.x + 192];
        float b = sq[threadIdx.x] + sq[threadIdx.x + 64] + sq[threadIdx.x + 128] + sq[threadIdx.x + 192];
        partial[(size_t)blockIdx.x * 128 + threadIdx.x] = a;
        partial[(size_t)blockIdx.x * 128 + 64 + threadIdx.x] = b;
    }
}

// ---- kred: reduce BN partials AND finish mu/rstd (64 blocks) ----
__global__ void kred(const float* __restrict__ partial, float* __restrict__ mu,
                     float* __restrict__ rstd, int G, int N) {
    __shared__ float s1[256], s2[256];
    int c = blockIdx.x;
    float a = 0.f, b = 0.f;
    for (int i = threadIdx.x; i < G; i += blockDim.x) {
        a += partial[(size_t)i * 128 + c];
        b += partial[(size_t)i * 128 + 64 + c];
    }
    s1[threadIdx.x] = a; s2[threadIdx.x] = b;
    __syncthreads();
    for (int off = 128; off >= 1; off >>= 1) {
        if (threadIdx.x < off) {
            s1[threadIdx.x] += s1[threadIdx.x + off];
            s2[threadIdx.x] += s2[threadIdx.x + off];
        }
        __syncthreads();
    }
    if (threadIdx.x == 0) {
        float m = s1[0] / (float)N;
        float v = s2[0] / (float)N - m * m;
        mu[c] = m;
        rstd[c] = rsqrtf(v + 1e-5f);
    }
}

// ---- k3c: recompute h from dstat -> BN -> ELU -> xl2, xr2 (wave per node) ----
__global__ void k3c(const float* __restrict__ x, const float* __restrict__ dstat,
                    const float* __restrict__ Wl1, const float* __restrict__ bl1,
                    const float* __restrict__ bias1,
                    const float* __restrict__ skW, const float* __restrict__ skb,
                    const float* __restrict__ mu, const float* __restrict__ rstd,
                    const float* __restrict__ gamma, const float* __restrict__ beta,
                    const float* __restrict__ Wl, const float* __restrict__ bl,
                    const float* __restrict__ Wr, const float* __restrict__ br,
                    float* __restrict__ xl2, float* __restrict__ xr2, int N) {
    __shared__ float sh[4][64];
    int w = threadIdx.x >> 6, lane = threadIdx.x & 63;
    int n = blockIdx.x * 4 + w;
    bool valid = (n < N);
    if (valid) {
        float hv = hcomp(dstat, x, Wl1, bl1, bias1, skW, skb, n, lane);
        hv = (hv - mu[lane]) * rstd[lane] * gamma[lane] + beta[lane];
        sh[w][lane] = elu1(hv);
    }
    __syncthreads();
    if (!valid) return;
    int c = lane & 31;
    const float* W = (lane < 32) ? Wl : Wr;
    const float* b = (lane < 32) ? bl : br;
    float acc = b[c];
    #pragma unroll
    for (int k = 0; k < 64; ++k) acc += sh[w][k] * W[k * 32 + c];
    ((lane < 32) ? xl2 : xr2)[(size_t)n * 32 + c] = acc;
}

// ---- kL2: 32 lanes per node = 4 edge-slots x 8 channel-lanes; packed-fp32.
//      Reads {src, ea} from 16B records; evS written in CSR order. ----
__global__ void __launch_bounds__(256, 4)
kL2(const float* __restrict__ xl2, const float* __restrict__ xr2,
    const float4* __restrict__ rec,
    const int* __restrict__ rowst, const int* __restrict__ cntA,
    const float* __restrict__ We, const float* __restrict__ att,
    float* __restrict__ evS, float* __restrict__ h2,
    float* __restrict__ denom2, int N) {
    int g = blockIdx.x * blockDim.x + threadIdx.x;
    int n = g >> 5;
    if (n >= N) return;
    int lane = g & 31;
    int slot = lane >> 3, cl = lane & 7;
    int c4 = cl * 4;
    float4 t4;
    t4 = *(const float4*)(We + c4);                      f2 weva = {t4.x, t4.y}, wevb = {t4.z, t4.w};
    t4 = *(const float4*)(att + c4);                     f2 atva = {t4.x, t4.y}, atvb = {t4.z, t4.w};
    t4 = *(const float4*)(xr2 + (size_t)n * 32 + c4);    f2 xrva = {t4.x, t4.y}, xrvb = {t4.z, t4.w};
    int start = rowst[n], len = cntA[n] + 1;
    float den = 0.f;
    f2 acca = {0.f, 0.f}, accb = {0.f, 0.f};

    for (int base = 0; base < len; base += 8) {
        int iA = base + slot, iB = base + 4 + slot;
        bool aA = iA < len, aB = iB < len;
        float4 qA = rec[start + (aA ? iA : 0)];
        float4 qB = rec[start + (aB ? iB : 0)];
        int sA = __float_as_int(qA.x), sB = __float_as_int(qB.x);
        float4 xA4 = *(const float4*)(xl2 + (size_t)sA * 32 + c4);
        float4 xB4 = *(const float4*)(xl2 + (size_t)sB * 32 + c4);
        f2 xAa = {xA4.x, xA4.y}, xAb = {xA4.z, xA4.w};
        f2 xBa = {xB4.x, xB4.y}, xBb = {xB4.z, xB4.w};
        float evA = qA.y, evB = qB.y;
        f2 mAa = xAa + xrva + evA * weva;
        f2 mAb = xAb + xrvb + evA * wevb;
        f2 mBa = xBa + xrva + evB * weva;
        f2 mBb = xBb + xrvb + evB * wevb;
        f2 psA = lrelu2(mAa) * atva + lrelu2(mAb) * atvb;
        f2 psB = lrelu2(mBa) * atva + lrelu2(mBb) * atvb;
        float pA = psA.x + psA.y;
        float pB = psB.x + psB.y;
        pA += __shfl_xor(pA, 1); pB += __shfl_xor(pB, 1);
        pA += __shfl_xor(pA, 2); pB += __shfl_xor(pB, 2);
        pA += __shfl_xor(pA, 4); pB += __shfl_xor(pB, 4);
        float eevA = aA ? __expf(pA) : 0.f;
        float eevB = aB ? __expf(pB) : 0.f;
        if (cl == 0) {
            if (aA) evS[start + iA] = eevA;
            if (aB) evS[start + iB] = eevB;
        }
        den += eevA + eevB;
        acca += eevA * xAa + eevB * xBa;
        accb += eevA * xAb + eevB * xBb;
    }
    #pragma unroll
    for (int m = 8; m <= 16; m <<= 1) {
        den    += __shfl_xor(den, m);
        acca.x += __shfl_xor(acca.x, m);
        acca.y += __shfl_xor(acca.y, m);
        accb.x += __shfl_xor(accb.x, m);
        accb.y += __shfl_xor(accb.y, m);
    }
    float inv = 1.f / (den + 1e-16f);
    if (slot == 0) {
        float4 o = make_float4(acca.x * inv, acca.y * inv, accb.x * inv, accb.y * inv);
        *(float4*)(h2 + (size_t)n * 32 + c4) = o;
    }
    if (lane == 0) denom2[n] = den;
}

// ---- k4c: alpha gather; pos recomputed from rankA (posA eliminated) ----
__global__ void k4c(const float* __restrict__ evS, const unsigned short* __restrict__ rankA,
                    const int* __restrict__ dstA, const int* __restrict__ rowst,
                    const int* __restrict__ cntA, const float* __restrict__ denom,
                    float* __restrict__ alpha, int E, int Et) {
    int t = blockIdx.x * blockDim.x + threadIdx.x;
    if (t >= Et) return;
    int d, pos;
    if (t < E) {
        d = dstA[t];
        pos = rowst[d] + min((int)rankA[t], cntA[d] - 1);
    } else {
        d = t - E;
        pos = rowst[d] + cntA[d];
    }
    alpha[t] = evS[pos] / (denom[d] + 1e-16f);
}

// ---- k5: h2 -> +bias2 -> elu -> two streamed MLP heads -> log_softmax ----
__global__ void __launch_bounds__(256, 1)
k5(const float* __restrict__ h2, const float* __restrict__ bias2,
   const float* __restrict__ Wt1, const float* __restrict__ bt1,
   const float* __restrict__ Wt2, const float* __restrict__ bt2,
   const float* __restrict__ Wc1, const float* __restrict__ bc1,
   const float* __restrict__ Wc2, const float* __restrict__ bc2,
   float* __restrict__ out, int N) {
    __shared__ float sWt1[1024], sWc1[1024], sWt2[640], sWc2[320];
    __shared__ float sbt1[32], sbc1[32], sbt2[20], sbc2[10], sb2[32];
    for (int i = threadIdx.x; i < 1024; i += blockDim.x) { sWt1[i] = Wt1[i]; sWc1[i] = Wc1[i]; }
    for (int i = threadIdx.x; i < 640; i += blockDim.x) sWt2[i] = Wt2[i];
    for (int i = threadIdx.x; i < 320; i += blockDim.x) sWc2[i] = Wc2[i];
    if (threadIdx.x < 32) { sbt1[threadIdx.x] = bt1[threadIdx.x]; sbc1[threadIdx.x] = bc1[threadIdx.x]; sb2[threadIdx.x] = bias2[threadIdx.x]; }
    if (threadIdx.x < 20) sbt2[threadIdx.x] = bt2[threadIdx.x];
    if (threadIdx.x < 10) sbc2[threadIdx.x] = bc2[threadIdx.x];
    __syncthreads();
    int n = blockIdx.x * blockDim.x + threadIdx.x;
    if (n >= N) return;
    float h[32];
    #pragma unroll
    for (int k = 0; k < 32; ++k) h[k] = elu1(h2[(size_t)n * 32 + k] + sb2[k]);
    float lt[20], lc[10];
    #pragma unroll
    for (int o = 0; o < 20; ++o) lt[o] = sbt2[o];
    #pragma unroll
    for (int o = 0; o < 10; ++o) lc[o] = sbc2[o];
    #pragma unroll
    for (int j = 0; j < 32; ++j) {
        float at = sbt1[j], ac = sbc1[j];
        #pragma unroll
        for (int k = 0; k < 32; ++k) { at += h[k] * sWt1[k * 32 + j]; ac += h[k] * sWc1[k * 32 + j]; }
        float tj = fmaxf(at, 0.f), cj = fmaxf(ac, 0.f);
        #pragma unroll
        for (int o = 0; o < 20; ++o) lt[o] += tj * sWt2[j * 20 + o];
        #pragma unroll
        for (int o = 0; o < 10; ++o) lc[o] += cj * sWc2[j * 10 + o];
    }
    float mt = -1e30f, mc = -1e30f;
    #pragma unroll
    for (int o = 0; o < 20; ++o) mt = fmaxf(mt, lt[o]);
    #pragma unroll
    for (int o = 0; o < 10; ++o) mc = fmaxf(mc, lc[o]);
    float st = 0.f, sc = 0.f;
    #pragma unroll
    for (int o = 0; o < 20; ++o) st += __expf(lt[o] - mt);
    #pragma unroll
    for (int o = 0; o < 10; ++o) sc += __expf(lc[o] - mc);
    float lset = mt + __logf(st);
    float lsec = mc + __logf(sc);
    #pragma unroll
    for (int o = 0; o < 10; ++o) out[(size_t)n * 30 + o] = lc[o] - lsec;
    #pragma unroll
    for (int o = 0; o < 20; ++o) out[(size_t)n * 30 + 10 + o] = lt[o] - lset;
}

extern "C" void kernel_launch(void* const* d_in, const int* in_sizes, int n_in,
                              void* d_out, int out_size, void* d_ws, size_t ws_size,
                              hipStream_t stream) {
    const float* x     = (const float*)d_in[0];
    const int*   ei    = (const int*)d_in[1];
    const float* eattr = (const float*)d_in[2];
    const float* Wl1   = (const float*)d_in[3];
    const float* bl1   = (const float*)d_in[4];
    const float* Wr1   = (const float*)d_in[5];
    const float* br1   = (const float*)d_in[6];
    const float* We1   = (const float*)d_in[7];
    const float* att1  = (const float*)d_in[8];
    const float* bias1 = (const float*)d_in[9];
    const float* skW   = (const float*)d_in[10];
    const float* skb   = (const float*)d_in[11];
    const float* gamma = (const float*)d_in[12];
    const float* beta  = (const float*)d_in[13];
    const float* Wl2   = (const float*)d_in[14];
    const float* bl2   = (const float*)d_in[15];
    const float* Wr2   = (const float*)d_in[16];
    const float* br2   = (const float*)d_in[17];
    const float* We2   = (const float*)d_in[18];
    const float* att2  = (const float*)d_in[19];
    const float* bias2 = (const float*)d_in[20];
    const float* Wc1   = (const float*)d_in[21];
    const float* bc1   = (const float*)d_in[22];
    const float* Wc2   = (const float*)d_in[23];
    const float* bc2   = (const float*)d_in[24];
    const float* Wt1   = (const float*)d_in[25];
    const float* bt1   = (const float*)d_in[26];
    const float* Wt2   = (const float*)d_in[27];
    const float* bt2   = (const float*)d_in[28];

    const int N  = in_sizes[0] / 2;
    const int E  = in_sizes[1] / 2;
    const int Et = E + N;
    const int* srcA = ei;
    const int* dstA = ei + E;
    const int G3 = 1024;
    const int B  = (N + 255) / 256;

    // workspace carve
    char* p = (char*)d_ws;
    unsigned long long* packed = (unsigned long long*)p; p += (size_t)N * 8;
    float4* rec   = (float4*)p; p += (size_t)Et * 16;     // 16B records
    unsigned short* rankA = (unsigned short*)p; p += (size_t)E * 2;
    float* h2     = (float*)p; p += (size_t)N * 32 * 4;
    float* xl2    = (float*)p; p += (size_t)N * 32 * 4;
    float* xr2    = (float*)p; p += (size_t)N * 32 * 4;
    float* evS    = (float*)p; p += (size_t)Et * 4;
    float* dstat  = (float*)p; p += (size_t)N * 6 * 4;
    int*   cntA   = (int*)p;   p += (size_t)N * 4;
    float* asumA  = (float*)p; p += (size_t)N * 4;
    int*   rowst  = (int*)p;   p += (size_t)N * 4;
    int*   bsum   = (int*)p;   p += 512 * 4;
    float* partial= (float*)p; p += (size_t)G3 * 128 * 4;
    float* mu     = (float*)p; p += 64 * 4;
    float* rstd   = (float*)p; p += 64 * 4;
    float* denom2 = (float*)p; p += (size_t)N * 4;

    float* outMain  = (float*)d_out;
    float* outAlpha = outMain + (size_t)N * 30;

    // ---- CSR build (ranks via k0p's atomic; kscatter computes L1 logits) ----
    hipMemsetAsync(packed, 0, (size_t)N * 8, stream);
    k0p<<<(E + 255) / 256, 256, 0, stream>>>(dstA, eattr, packed, rankA, E);
    kscanA<<<B, 256, 0, stream>>>(packed, rowst, bsum, cntA, asumA, N);
    kscanB<<<1, 512, 0, stream>>>(bsum, B);
    kscanC<<<B, 256, 0, stream>>>(rowst, bsum, N);
    kscatter<<<(Et + 255) / 256, 256, 0, stream>>>(srcA, dstA, eattr, x, asumA, cntA,
                                                   rowst, rankA,
                                                   Wl1, bl1, Wr1, br1, We1, att1,
                                                   rec, E, Et);

    // ---- layer 1 moment-sum (light segmented sum) ----
    kL1<<<(N + 15) / 16, 256, 0, stream>>>(rec, x, rowst, cntA, dstat, N);

    // ---- BN stats (h never materialized) + layer-2 node transforms ----
    k3a<<<G3, 256, 0, stream>>>(x, dstat, Wl1, bl1, bias1, skW, skb, partial, N);
    kred<<<64, 256, 0, stream>>>(partial, mu, rstd, G3, N);
    k3c<<<(N + 3) / 4, 256, 0, stream>>>(x, dstat, Wl1, bl1, bias1, skW, skb,
                                         mu, rstd, gamma, beta,
                                         Wl2, bl2, Wr2, br2, xl2, xr2, N);

    // ---- layer 2 (gather, zero atomics, packed fp32, coalesced evS) ----
    kL2<<<((size_t)N * 32 + 255) / 256, 256, 0, stream>>>(xl2, xr2, rec, rowst, cntA,
                                                          We2, att2, evS, h2, denom2, N);
    k4c<<<(Et + 255) / 256, 256, 0, stream>>>(evS, rankA, dstA, rowst, cntA, denom2,
                                              outAlpha, E, Et);

    // ---- heads ----
    k5<<<(N + 255) / 256, 256, 0, stream>>>(h2, bias2, Wt1, bt1, Wt2, bt2,
                                            Wc1, bc1, Wc2, bc2, outMain, N);
    (void)n_in; (void)out_size; (void)ws_size;
}

// Round 19
// 324.723 us; speedup vs baseline: 1.0557x; 1.0557x over previous
//
#include <hip/hip_runtime.h>
#include <math.h>

#define NEG_SLOPE 0.2f
#define CNT_SHIFT 44
#define LOW_MASK ((1ULL << CNT_SHIFT) - 1)
#define EA_SCALE 262144.0f          // 2^18 fixed-point for edge_attr sums
#define EA_INV (1.0f / 262144.0f)

typedef float f2 __attribute__((ext_vector_type(2)));
__device__ __forceinline__ f2 max2(f2 a, f2 b) { return __builtin_elementwise_max(a, b); }
__device__ __forceinline__ f2 lrelu2(f2 m) { return max2(m, m * NEG_SLOPE); }

__device__ __forceinline__ float lrelu(float x) { return fmaxf(x, NEG_SLOPE * x); }
__device__ __forceinline__ float elu1(float x) { return x > 0.f ? x : __expf(x) - 1.f; }

// Record layout (16B): {src_bits, ea, ev0, ev1}
//   kL2 uses (src, ea); kL1 uses (ev0, ev1) + regathers x[src] (L2-hot).

// ---- k0p: single u64 atomic per edge (rank capture). Pure latency kernel
//      at the ~21 G scattered-atomics/s wall (proven flat R13/R15/R16/R18). ----
__global__ void k0p(const int* __restrict__ dst, const float* __restrict__ ea,
                    unsigned long long* __restrict__ packed,
                    unsigned short* __restrict__ rankA, int E) {
    int t = blockIdx.x * blockDim.x + threadIdx.x;
    if (t >= E) return;
    int d = dst[t];
    unsigned long long inc = (1ULL << CNT_SHIFT)
                           | (unsigned long long)__float2uint_rn(ea[t] * EA_SCALE);
    unsigned long long old = atomicAdd(&packed[d], inc);
    rankA[t] = (unsigned short)(old >> CNT_SHIFT);
}

// ---- kscanA: per-block inclusive scan of (cnt[i]+1); unpack cnt/asum ----
__global__ void kscanA(const unsigned long long* __restrict__ packed,
                       int* __restrict__ rowstart, int* __restrict__ bsum,
                       int* __restrict__ cntA, float* __restrict__ asumA, int N) {
    __shared__ int sm[256];
    int t = threadIdx.x;
    int i = blockIdx.x * 256 + t;
    int v = 0;
    if (i < N) {
        unsigned long long p = packed[i];
        int c = (int)(p >> CNT_SHIFT);
        cntA[i] = c;
        asumA[i] = (float)(p & LOW_MASK) * EA_INV;
        v = c + 1;
    }
    sm[t] = v;
    __syncthreads();
    for (int off = 1; off < 256; off <<= 1) {
        int u = (t >= off) ? sm[t - off] : 0;
        __syncthreads();
        sm[t] += u;
        __syncthreads();
    }
    if (i < N) rowstart[i] = sm[t] - v;
    if (t == 255) bsum[blockIdx.x] = sm[255];
}

__global__ void kscanB(int* __restrict__ bsum, int B) {
    __shared__ int sm[512];
    int t = threadIdx.x;
    int v = (t < B) ? bsum[t] : 0;
    sm[t] = v;
    __syncthreads();
    for (int off = 1; off < 512; off <<= 1) {
        int u = (t >= off) ? sm[t - off] : 0;
        __syncthreads();
        sm[t] += u;
        __syncthreads();
    }
    if (t < B) bsum[t] = sm[t] - v;  // exclusive block offsets
}

__global__ void kscanC(int* __restrict__ rowstart, const int* __restrict__ bsum, int N) {
    int i = blockIdx.x * blockDim.x + threadIdx.x;
    if (i < N) rowstart[i] += bsum[i >> 8];
}

// ---- kscatter: pos = rowst[d] + rank[t]; zero atomics, idempotent.
//      Computes the layer-1 logit/exp here (latency slack under the
//      scattered 16B record write); records are 16B = {src, ea, ev0, ev1}. ----
__global__ void kscatter(const int* __restrict__ srcA, const int* __restrict__ dstA,
                         const float* __restrict__ ea, const float* __restrict__ x,
                         const float* __restrict__ asumA,
                         const int* __restrict__ cntA, const int* __restrict__ rowstart,
                         const unsigned short* __restrict__ rankA,
                         const float* __restrict__ Wl, const float* __restrict__ bl,
                         const float* __restrict__ Wr, const float* __restrict__ br,
                         const float* __restrict__ We, const float* __restrict__ att,
                         float4* __restrict__ rec, int* __restrict__ posA, int E, int Et) {
    __shared__ float sW[7][64];
    if (threadIdx.x < 64) {
        int d = threadIdx.x;
        sW[0][d] = Wl[d];  sW[1][d] = Wl[64 + d];
        sW[2][d] = We[d];  sW[3][d] = att[d];
        sW[4][d] = Wr[d];  sW[5][d] = Wr[64 + d];
        sW[6][d] = bl[d] + br[d];
    }
    __syncthreads();
    int t = blockIdx.x * blockDim.x + threadIdx.x;
    if (t >= Et) return;
    int s, d, pos; float eav;
    if (t < E) {
        d = dstA[t]; s = srcA[t]; eav = ea[t];
        int r = min((int)rankA[t], cntA[d] - 1);   // defensive clamp (replay safety)
        pos = rowstart[d] + r;
        posA[t] = pos;
    } else {
        d = t - E; s = d;
        int cd = cntA[d];
        pos = rowstart[d] + cd;
        eav = asumA[d] / fmaxf((float)cd, 1.0f);
    }
    float2 xs = ((const float2*)x)[s];
    float2 xd = ((const float2*)x)[d];
    float l0 = 0.f, l1 = 0.f;
    #pragma unroll
    for (int c = 0; c < 32; ++c) {
        float m0 = xd.x * sW[4][c] + xd.y * sW[5][c] + sW[6][c]
                 + xs.x * sW[0][c] + xs.y * sW[1][c] + eav * sW[2][c];
        l0 += lrelu(m0) * sW[3][c];
        int c2 = c + 32;
        float m1 = xd.x * sW[4][c2] + xd.y * sW[5][c2] + sW[6][c2]
                 + xs.x * sW[0][c2] + xs.y * sW[1][c2] + eav * sW[2][c2];
        l1 += lrelu(m1) * sW[3][c2];
    }
    rec[pos] = make_float4(__int_as_float(s), eav, __expf(l0), __expf(l1));
}

// ---- kL1: light segmented moment-sum. 16 lanes per node; 16B rec +
//      8B x[src] regather (L2-hot 800KB table). ----
__global__ void kL1(const float4* __restrict__ rec, const float* __restrict__ x,
                    const int* __restrict__ rowst, const int* __restrict__ cntA,
                    float* __restrict__ dstat, int N) {
    int g = threadIdx.x >> 4, l16 = threadIdx.x & 15;
    int n = blockIdx.x * 16 + g;
    if (n >= N) return;
    int start = rowst[n], len = cntA[n] + 1;
    float pd0 = 0.f, pd1 = 0.f, pa0 = 0.f, pa1 = 0.f, pb0 = 0.f, pb1 = 0.f;
    for (int i = l16; i < len; i += 16) {
        float4 q = rec[start + i];            // {src_bits, ea, ev0, ev1}
        float2 xs = ((const float2*)x)[__float_as_int(q.x)];
        pd0 += q.z;        pd1 += q.w;
        pa0 += q.z * xs.x; pa1 += q.w * xs.x;
        pb0 += q.z * xs.y; pb1 += q.w * xs.y;
    }
    #pragma unroll
    for (int m = 1; m < 16; m <<= 1) {
        pd0 += __shfl_xor(pd0, m); pd1 += __shfl_xor(pd1, m);
        pa0 += __shfl_xor(pa0, m); pa1 += __shfl_xor(pa1, m);
        pb0 += __shfl_xor(pb0, m); pb1 += __shfl_xor(pb1, m);
    }
    if (l16 == 0) {
        float* ps = &dstat[(size_t)n * 6];
        ps[0] = pd0; ps[1] = pd1;
        ps[2] = pa0; ps[3] = pa1;
        ps[4] = pb0; ps[5] = pb1;
    }
}

// ---- k3a: reconstruct h = agg/denom + bias1 + skip; BN partials ----
__global__ void k3a(const float* __restrict__ x, const float* __restrict__ dstat,
                    const float* __restrict__ Wl, const float* __restrict__ bl,
                    const float* __restrict__ bias1,
                    const float* __restrict__ skW, const float* __restrict__ skb,
                    float* __restrict__ hout, float* __restrict__ partial, int N) {
    __shared__ float sv[256], sq[256];
    size_t total = (size_t)N * 64;
    size_t stride = (size_t)gridDim.x * blockDim.x;
    float s = 0.f, q = 0.f;
    for (size_t idx = (size_t)blockIdx.x * blockDim.x + threadIdx.x; idx < total; idx += stride) {
        int n = (int)(idx >> 6), d = (int)(idx & 63), h2 = d >> 5;
        const float* ps = &dstat[(size_t)n * 6];
        float den = ps[h2], t0 = ps[2 + h2], t1 = ps[4 + h2];
        float agg = t0 * Wl[d] + t1 * Wl[64 + d] + den * bl[d];
        float hv = agg / (den + 1e-16f) + bias1[d]
                 + x[2 * n] * skW[d] + x[2 * n + 1] * skW[64 + d] + skb[d];
        hout[idx] = hv;
        s += hv; q += hv * hv;
    }
    sv[threadIdx.x] = s; sq[threadIdx.x] = q;
    __syncthreads();
    if (threadIdx.x < 64) {
        float a = sv[threadIdx.x] + sv[threadIdx.x + 64] + sv[threadIdx.x + 128] + sv[threadIdx.x + 192];
        float b = sq[threadIdx.x] + sq[threadIdx.x + 64] + sq[threadIdx.x + 128] + sq[threadIdx.x + 192];
        partial[(size_t)blockIdx.x * 128 + threadIdx.x] = a;
        partial[(size_t)blockIdx.x * 128 + 64 + threadIdx.x] = b;
    }
}

// ---- kred: reduce BN partials AND finish mu/rstd (64 blocks) ----
__global__ void kred(const float* __restrict__ partial, float* __restrict__ mu,
                     float* __restrict__ rstd, int G, int N) {
    __shared__ float s1[256], s2[256];
    int c = blockIdx.x;
    float a = 0.f, b = 0.f;
    for (int i = threadIdx.x; i < G; i += blockDim.x) {
        a += partial[(size_t)i * 128 + c];
        b += partial[(size_t)i * 128 + 64 + c];
    }
    s1[threadIdx.x] = a; s2[threadIdx.x] = b;
    __syncthreads();
    for (int off = 128; off >= 1; off >>= 1) {
        if (threadIdx.x < off) {
            s1[threadIdx.x] += s1[threadIdx.x + off];
            s2[threadIdx.x] += s2[threadIdx.x + off];
        }
        __syncthreads();
    }
    if (threadIdx.x == 0) {
        float m = s1[0] / (float)N;
        float v = s2[0] / (float)N - m * m;
        mu[c] = m;
        rstd[c] = rsqrtf(v + 1e-5f);
    }
}

// ---- k3c: BN + ELU -> xl2, xr2 (wave per node) ----
__global__ void k3c(const float* __restrict__ h, const float* __restrict__ mu,
                    const float* __restrict__ rstd, const float* __restrict__ gamma,
                    const float* __restrict__ beta,
                    const float* __restrict__ Wl, const float* __restrict__ bl,
                    const float* __restrict__ Wr, const float* __restrict__ br,
                    float* __restrict__ xl2, float* __restrict__ xr2, int N) {
    __shared__ float sh[4][64];
    int w = threadIdx.x >> 6, lane = threadIdx.x & 63;
    int n = blockIdx.x * 4 + w;
    bool valid = (n < N);
    if (valid) {
        float hv = h[(size_t)n * 64 + lane];
        hv = (hv - mu[lane]) * rstd[lane] * gamma[lane] + beta[lane];
        sh[w][lane] = elu1(hv);
    }
    __syncthreads();
    if (!valid) return;
    int c = lane & 31;
    const float* W = (lane < 32) ? Wl : Wr;
    const float* b = (lane < 32) ? bl : br;
    float acc = b[c];
    #pragma unroll
    for (int k = 0; k < 64; ++k) acc += sh[w][k] * W[k * 32 + c];
    ((lane < 32) ? xl2 : xr2)[(size_t)n * 32 + c] = acc;
}

// ---- kL2: 32 lanes per node = 4 edge-slots x 8 channel-lanes; packed-fp32.
//      Reads {src, ea} from 16B records; evS written in CSR order. ----
__global__ void __launch_bounds__(256, 4)
kL2(const float* __restrict__ xl2, const float* __restrict__ xr2,
    const float4* __restrict__ rec,
    const int* __restrict__ rowst, const int* __restrict__ cntA,
    const float* __restrict__ We, const float* __restrict__ att,
    float* __restrict__ evS, float* __restrict__ h2,
    float* __restrict__ denom2, int N) {
    int g = blockIdx.x * blockDim.x + threadIdx.x;
    int n = g >> 5;
    if (n >= N) return;
    int lane = g & 31;
    int slot = lane >> 3, cl = lane & 7;
    int c4 = cl * 4;
    float4 t4;
    t4 = *(const float4*)(We + c4);                      f2 weva = {t4.x, t4.y}, wevb = {t4.z, t4.w};
    t4 = *(const float4*)(att + c4);                     f2 atva = {t4.x, t4.y}, atvb = {t4.z, t4.w};
    t4 = *(const float4*)(xr2 + (size_t)n * 32 + c4);    f2 xrva = {t4.x, t4.y}, xrvb = {t4.z, t4.w};
    int start = rowst[n], len = cntA[n] + 1;
    float den = 0.f;
    f2 acca = {0.f, 0.f}, accb = {0.f, 0.f};

    for (int base = 0; base < len; base += 8) {
        int iA = base + slot, iB = base + 4 + slot;
        bool aA = iA < len, aB = iB < len;
        float4 qA = rec[start + (aA ? iA : 0)];
        float4 qB = rec[start + (aB ? iB : 0)];
        int sA = __float_as_int(qA.x), sB = __float_as_int(qB.x);
        float4 xA4 = *(const float4*)(xl2 + (size_t)sA * 32 + c4);
        float4 xB4 = *(const float4*)(xl2 + (size_t)sB * 32 + c4);
        f2 xAa = {xA4.x, xA4.y}, xAb = {xA4.z, xA4.w};
        f2 xBa = {xB4.x, xB4.y}, xBb = {xB4.z, xB4.w};
        float evA = qA.y, evB = qB.y;
        f2 mAa = xAa + xrva + evA * weva;
        f2 mAb = xAb + xrvb + evA * wevb;
        f2 mBa = xBa + xrva + evB * weva;
        f2 mBb = xBb + xrvb + evB * wevb;
        f2 psA = lrelu2(mAa) * atva + lrelu2(mAb) * atvb;
        f2 psB = lrelu2(mBa) * atva + lrelu2(mBb) * atvb;
        float pA = psA.x + psA.y;
        float pB = psB.x + psB.y;
        pA += __shfl_xor(pA, 1); pB += __shfl_xor(pB, 1);
        pA += __shfl_xor(pA, 2); pB += __shfl_xor(pB, 2);
        pA += __shfl_xor(pA, 4); pB += __shfl_xor(pB, 4);
        float eevA = aA ? __expf(pA) : 0.f;
        float eevB = aB ? __expf(pB) : 0.f;
        if (cl == 0) {
            if (aA) evS[start + iA] = eevA;
            if (aB) evS[start + iB] = eevB;
        }
        den += eevA + eevB;
        acca += eevA * xAa + eevB * xBa;
        accb += eevA * xAb + eevB * xBb;
    }
    #pragma unroll
    for (int m = 8; m <= 16; m <<= 1) {
        den    += __shfl_xor(den, m);
        acca.x += __shfl_xor(acca.x, m);
        acca.y += __shfl_xor(acca.y, m);
        accb.x += __shfl_xor(accb.x, m);
        accb.y += __shfl_xor(accb.y, m);
    }
    float inv = 1.f / (den + 1e-16f);
    if (slot == 0) {
        float4 o = make_float4(acca.x * inv, acca.y * inv, accb.x * inv, accb.y * inv);
        *(float4*)(h2 + (size_t)n * 32 + c4) = o;
    }
    if (lane == 0) denom2[n] = den;
}

// ---- k4c: alpha gather (coalesced writes; evS reads hit L2/LLC) ----
__global__ void k4c(const float* __restrict__ evS, const int* __restrict__ posA,
                    const int* __restrict__ dstA, const int* __restrict__ rowst,
                    const int* __restrict__ cntA, const float* __restrict__ denom,
                    float* __restrict__ alpha, int E, int Et) {
    int t = blockIdx.x * blockDim.x + threadIdx.x;
    if (t >= Et) return;
    float ev, den;
    if (t < E) {
        ev = evS[posA[t]];
        den = denom[dstA[t]];
    } else {
        int d = t - E;
        ev = evS[rowst[d] + cntA[d]];
        den = denom[d];
    }
    alpha[t] = ev / (den + 1e-16f);
}

// ---- k5: h2 -> +bias2 -> elu -> two streamed MLP heads -> log_softmax ----
__global__ void __launch_bounds__(256, 1)
k5(const float* __restrict__ h2, const float* __restrict__ bias2,
   const float* __restrict__ Wt1, const float* __restrict__ bt1,
   const float* __restrict__ Wt2, const float* __restrict__ bt2,
   const float* __restrict__ Wc1, const float* __restrict__ bc1,
   const float* __restrict__ Wc2, const float* __restrict__ bc2,
   float* __restrict__ out, int N) {
    __shared__ float sWt1[1024], sWc1[1024], sWt2[640], sWc2[320];
    __shared__ float sbt1[32], sbc1[32], sbt2[20], sbc2[10], sb2[32];
    for (int i = threadIdx.x; i < 1024; i += blockDim.x) { sWt1[i] = Wt1[i]; sWc1[i] = Wc1[i]; }
    for (int i = threadIdx.x; i < 640; i += blockDim.x) sWt2[i] = Wt2[i];
    for (int i = threadIdx.x; i < 320; i += blockDim.x) sWc2[i] = Wc2[i];
    if (threadIdx.x < 32) { sbt1[threadIdx.x] = bt1[threadIdx.x]; sbc1[threadIdx.x] = bc1[threadIdx.x]; sb2[threadIdx.x] = bias2[threadIdx.x]; }
    if (threadIdx.x < 20) sbt2[threadIdx.x] = bt2[threadIdx.x];
    if (threadIdx.x < 10) sbc2[threadIdx.x] = bc2[threadIdx.x];
    __syncthreads();
    int n = blockIdx.x * blockDim.x + threadIdx.x;
    if (n >= N) return;
    float h[32];
    #pragma unroll
    for (int k = 0; k < 32; ++k) h[k] = elu1(h2[(size_t)n * 32 + k] + sb2[k]);
    float lt[20], lc[10];
    #pragma unroll
    for (int o = 0; o < 20; ++o) lt[o] = sbt2[o];
    #pragma unroll
    for (int o = 0; o < 10; ++o) lc[o] = sbc2[o];
    #pragma unroll
    for (int j = 0; j < 32; ++j) {
        float at = sbt1[j], ac = sbc1[j];
        #pragma unroll
        for (int k = 0; k < 32; ++k) { at += h[k] * sWt1[k * 32 + j]; ac += h[k] * sWc1[k * 32 + j]; }
        float tj = fmaxf(at, 0.f), cj = fmaxf(ac, 0.f);
        #pragma unroll
        for (int o = 0; o < 20; ++o) lt[o] += tj * sWt2[j * 20 + o];
        #pragma unroll
        for (int o = 0; o < 10; ++o) lc[o] += cj * sWc2[j * 10 + o];
    }
    float mt = -1e30f, mc = -1e30f;
    #pragma unroll
    for (int o = 0; o < 20; ++o) mt = fmaxf(mt, lt[o]);
    #pragma unroll
    for (int o = 0; o < 10; ++o) mc = fmaxf(mc, lc[o]);
    float st = 0.f, sc = 0.f;
    #pragma unroll
    for (int o = 0; o < 20; ++o) st += __expf(lt[o] - mt);
    #pragma unroll
    for (int o = 0; o < 10; ++o) sc += __expf(lc[o] - mc);
    float lset = mt + __logf(st);
    float lsec = mc + __logf(sc);
    #pragma unroll
    for (int o = 0; o < 10; ++o) out[(size_t)n * 30 + o] = lc[o] - lsec;
    #pragma unroll
    for (int o = 0; o < 20; ++o) out[(size_t)n * 30 + 10 + o] = lt[o] - lset;
}

extern "C" void kernel_launch(void* const* d_in, const int* in_sizes, int n_in,
                              void* d_out, int out_size, void* d_ws, size_t ws_size,
                              hipStream_t stream) {
    const float* x     = (const float*)d_in[0];
    const int*   ei    = (const int*)d_in[1];
    const float* eattr = (const float*)d_in[2];
    const float* Wl1   = (const float*)d_in[3];
    const float* bl1   = (const float*)d_in[4];
    const float* Wr1   = (const float*)d_in[5];
    const float* br1   = (const float*)d_in[6];
    const float* We1   = (const float*)d_in[7];
    const float* att1  = (const float*)d_in[8];
    const float* bias1 = (const float*)d_in[9];
    const float* skW   = (const float*)d_in[10];
    const float* skb   = (const float*)d_in[11];
    const float* gamma = (const float*)d_in[12];
    const float* beta  = (const float*)d_in[13];
    const float* Wl2   = (const float*)d_in[14];
    const float* bl2   = (const float*)d_in[15];
    const float* Wr2   = (const float*)d_in[16];
    const float* br2   = (const float*)d_in[17];
    const float* We2   = (const float*)d_in[18];
    const float* att2  = (const float*)d_in[19];
    const float* bias2 = (const float*)d_in[20];
    const float* Wc1   = (const float*)d_in[21];
    const float* bc1   = (const float*)d_in[22];
    const float* Wc2   = (const float*)d_in[23];
    const float* bc2   = (const float*)d_in[24];
    const float* Wt1   = (const float*)d_in[25];
    const float* bt1   = (const float*)d_in[26];
    const float* Wt2   = (const float*)d_in[27];
    const float* bt2   = (const float*)d_in[28];

    const int N  = in_sizes[0] / 2;
    const int E  = in_sizes[1] / 2;
    const int Et = E + N;
    const int* srcA = ei;
    const int* dstA = ei + E;
    const int G3 = 1024;
    const int B  = (N + 255) / 256;

    // workspace carve
    char* p = (char*)d_ws;
    unsigned long long* packed = (unsigned long long*)p; p += (size_t)N * 8;
    float4* rec   = (float4*)p; p += (size_t)Et * 16;     // 16B records
    int*   posA   = (int*)p;   p += (size_t)E * 4;
    unsigned short* rankA = (unsigned short*)p; p += (size_t)E * 2;
    float* hbuf   = (float*)p; p += (size_t)N * 64 * 4;   // h rows; reused as h2 (N*32)
    float* xl2    = (float*)p; p += (size_t)N * 32 * 4;
    float* xr2    = (float*)p; p += (size_t)N * 32 * 4;
    float* evS    = (float*)p; p += (size_t)Et * 4;
    float* dstat  = (float*)p; p += (size_t)N * 6 * 4;
    int*   cntA   = (int*)p;   p += (size_t)N * 4;
    float* asumA  = (float*)p; p += (size_t)N * 4;
    int*   rowst  = (int*)p;   p += (size_t)N * 4;
    int*   bsum   = (int*)p;   p += 512 * 4;
    float* partial= (float*)p; p += (size_t)G3 * 128 * 4;
    float* mu     = (float*)p; p += 64 * 4;
    float* rstd   = (float*)p; p += 64 * 4;
    float* denom2 = (float*)p; p += (size_t)N * 4;
    float* h2     = hbuf;

    float* outMain  = (float*)d_out;
    float* outAlpha = outMain + (size_t)N * 30;

    // ---- CSR build (ranks via k0p's atomic; kscatter computes L1 logits) ----
    hipMemsetAsync(packed, 0, (size_t)N * 8, stream);
    k0p<<<(E + 255) / 256, 256, 0, stream>>>(dstA, eattr, packed, rankA, E);
    kscanA<<<B, 256, 0, stream>>>(packed, rowst, bsum, cntA, asumA, N);
    kscanB<<<1, 512, 0, stream>>>(bsum, B);
    kscanC<<<B, 256, 0, stream>>>(rowst, bsum, N);
    kscatter<<<(Et + 255) / 256, 256, 0, stream>>>(srcA, dstA, eattr, x, asumA, cntA,
                                                   rowst, rankA,
                                                   Wl1, bl1, Wr1, br1, We1, att1,
                                                   rec, posA, E, Et);

    // ---- layer 1 moment-sum (light segmented sum) ----
    kL1<<<(N + 15) / 16, 256, 0, stream>>>(rec, x, rowst, cntA, dstat, N);

    // ---- node reconstruction + skip + BN ----
    k3a<<<G3, 256, 0, stream>>>(x, dstat, Wl1, bl1, bias1, skW, skb, hbuf, partial, N);
    kred<<<64, 256, 0, stream>>>(partial, mu, rstd, G3, N);
    k3c<<<(N + 3) / 4, 256, 0, stream>>>(hbuf, mu, rstd, gamma, beta,
                                         Wl2, bl2, Wr2, br2, xl2, xr2, N);

    // ---- layer 2 (gather, zero atomics, packed fp32, coalesced evS) ----
    kL2<<<((size_t)N * 32 + 255) / 256, 256, 0, stream>>>(xl2, xr2, rec, rowst, cntA,
                                                          We2, att2, evS, h2, denom2, N);
    k4c<<<(Et + 255) / 256, 256, 0, stream>>>(evS, posA, dstA, rowst, cntA, denom2,
                                              outAlpha, E, Et);

    // ---- heads ----
    k5<<<(N + 255) / 256, 256, 0, stream>>>(h2, bias2, Wt1, bt1, Wt2, bt2,
                                            Wc1, bc1, Wc2, bc2, outMain, N);
    (void)n_in; (void)out_size; (void)ws_size;
}